// Round 8
// baseline (299.927 us; speedup 1.0000x reference)
//
#include <hip/hip_runtime.h>
#include <hip/hip_bf16.h>
#include <math.h>

#define B_   16
#define T_   576
#define NH_  12

typedef unsigned short u16;
typedef __attribute__((ext_vector_type(8))) short bf16x8;
typedef __attribute__((ext_vector_type(4))) float f32x4;

// ---------------------------------------------------------------------------
// helpers
// ---------------------------------------------------------------------------
__device__ __forceinline__ float bf2f(u16 u) {
    union { unsigned int i; float f; } x; x.i = ((unsigned int)u) << 16; return x.f;
}
__device__ __forceinline__ u16 f2bf(float f) {   // round-to-nearest-even
    union { float f; unsigned int i; } x; x.f = f;
    unsigned int r = x.i + 0x7fffu + ((x.i >> 16) & 1u);
    return (u16)(r >> 16);
}
__device__ __forceinline__ void splitf(float v, u16& h, u16& l) {
    h = f2bf(v);
    l = f2bf(v - bf2f(h));
}
__device__ __forceinline__ void gld_lds16(const u16* g, u16* l) {
    __builtin_amdgcn_global_load_lds(
        (const __attribute__((address_space(1))) unsigned int*)g,
        (__attribute__((address_space(3))) unsigned int*)l, 16, 0, 0);
}
__device__ __forceinline__ float exp2f_(float x) {
#if __has_builtin(__builtin_amdgcn_exp2f)
    return __builtin_amdgcn_exp2f(x);
#else
    return exp2f(x);
#endif
}

#define VMBAR() do { \
    asm volatile("s_waitcnt vmcnt(0)" ::: "memory"); \
    __builtin_amdgcn_s_barrier(); \
    __builtin_amdgcn_sched_barrier(0); } while (0)

// ---------------------------------------------------------------------------
// prep_all: blocks [0,3456) convert x to bf16; [3456,5952) weight transposes
// ---------------------------------------------------------------------------
__global__ __launch_bounds__(256)
void prep_all(const float* __restrict__ x, u16* __restrict__ x_bf,
              const float* __restrict__ wq, const float* __restrict__ wdkv,
              const float* __restrict__ uk1, const float* __restrict__ uv1,
              const float* __restrict__ uk2, const float* __restrict__ uv2,
              const float* __restrict__ uk4, const float* __restrict__ uv4,
              const float* __restrict__ wout,
              u16* wqT, u16* wdkvT, u16* uk1T, u16* uv1T, u16* uk2T,
              u16* uv2T, u16* uk4T, u16* uv4T, u16* woutTh, u16* woutTl) {
    __shared__ float t[32][33];
    int id = blockIdx.x;
    if (id < 3456) {
        const int i8 = (id * 256 + threadIdx.x) * 8;
        const float4 a = *(const float4*)&x[i8];
        const float4 b = *(const float4*)&x[i8 + 4];
        u16 o[8] = {f2bf(a.x),f2bf(a.y),f2bf(a.z),f2bf(a.w),
                    f2bf(b.x),f2bf(b.y),f2bf(b.z),f2bf(b.w)};
        *(bf16x8*)&x_bf[i8] = *(bf16x8*)o;
        return;
    }
    id -= 3456;
    const float* W; u16* Th; u16* Tl = nullptr; int K, N, gx; bool split = false;
    if (id < 576)       { W = wq;  Th = wqT;  K = 768; N = 768; gx = 24; }
    else if (id < 768)  { id -= 576; W = wdkv; Th = wdkvT; K = 768; N = 256; gx = 8; }
    else if (id < 1920) {
        id -= 768; const int w = id / 192; id -= w * 192;
        const float* Ws[6] = {uk1, uv1, uk2, uv2, uk4, uv4};
        u16* Ts[6] = {uk1T, uv1T, uk2T, uv2T, uk4T, uv4T};
        W = Ws[w]; Th = Ts[w]; K = 256; N = 768; gx = 24;
    } else { id -= 1920; W = wout; Th = woutTh; Tl = woutTl; K = 768; N = 768; gx = 24; split = true; }
    const int bx = id % gx, by = id / gx;
    const int n0 = bx * 32, k0 = by * 32;
    const int tid = threadIdx.x;
    const int c  = tid & 31;
    const int r4 = tid >> 5;
#pragma unroll
    for (int i = 0; i < 4; ++i)
        t[r4*4+i][c] = W[(size_t)(k0 + r4*4 + i) * N + n0 + c];
    __syncthreads();
#pragma unroll
    for (int i = 0; i < 4; ++i) {
        const float v = t[c][r4*4+i];
        const size_t o = (size_t)(n0 + r4*4 + i) * K + k0 + c;
        if (split) { u16 h, l; splitf(v, h, l); Th[o] = h; Tl[o] = l; }
        else       { Th[o] = f2bf(v); }
    }
}

// ---------------------------------------------------------------------------
// MFMA GEMM device body (shared by the generic global and kv_fused).
// B transposed [N][K]. 128x128 tile, BK=64, 4 waves.
// OM: 0 = fp32(+bias), 1 = bf16 [M][N], 2 = bf16 [b][N][KStS] (key=row%KStL)
// ---------------------------------------------------------------------------
template<bool IN_SPLIT, int OM1, int OM2, bool HAS_BIAS>
__device__ __forceinline__ void gemm_body(
               u16* smem, int bx, int by,
               const u16* __restrict__ Ah, const u16* __restrict__ Al,
               const u16* __restrict__ B1h, const u16* __restrict__ B1l,
               const u16* __restrict__ B2h,
               const float* __restrict__ bias, float* __restrict__ C1f,
               u16* __restrict__ C1bf, u16* __restrict__ C2bf,
               int M, int N1, int N2, int K, int KStL, int KStS) {
    const int tid  = threadIdx.x;
    const int wid  = tid >> 6;
    const int lane = tid & 63;
    const int lr   = lane & 15;
    const int kg   = lane >> 4;
    const int wr   = wid >> 1, wc = wid & 1;
    const int m0   = by * 128;
    const int n0   = bx * 128;
    const bool second = (OM2 >= 0) && (n0 >= N1);
    const int nb   = second ? n0 - N1 : n0;
    const int subrow = lane >> 3;
    const int gslot  = (lane & 7) ^ subrow;     // inverse swizzle on source

    const u16* src; int rowbase; bool isA; u16* tile;
    constexpr int NITER = IN_SPLIT ? 16 : 8;
    if (IN_SPLIT) {
        src = (wid == 0) ? Ah : (wid == 1) ? Al : (wid == 2) ? B1h : B1l;
        rowbase = (wid < 2) ? m0 : n0;
        isA = (wid < 2);
        tile = smem + wid * 8192;
    } else {
        const u16* Bsel = second ? B2h : B1h;
        src = (wid < 2) ? Ah : Bsel;
        rowbase = ((wid < 2) ? m0 : nb) + (wid & 1) * 64;
        isA = (wid < 2);
        tile = smem + (wid >> 1) * 8192 + (wid & 1) * 4096;
    }

    f32x4 acc[4][4];
#pragma unroll
    for (int i = 0; i < 4; ++i)
#pragma unroll
        for (int j = 0; j < 4; ++j) acc[i][j] = (f32x4)(0.f);

    for (int k0 = 0; k0 < K; k0 += 64) {
#pragma unroll
        for (int i = 0; i < NITER; ++i) {
            int grow = rowbase + i*8 + subrow;
            if (isA && grow >= M) grow = M - 1;   // clamp tail (dup loads ok)
            gld_lds16(src + (size_t)grow * K + (k0 + gslot * 8), tile + i * 512);
        }
        __syncthreads();
#pragma unroll
        for (int ks = 0; ks < 2; ++ks) {
            const int slot = (ks*4 + kg) ^ (lr & 7);
            bf16x8 ah[4], bh[4], al[4], bl[4];
#pragma unroll
            for (int i = 0; i < 4; ++i) {
                const int offA = (wr*64 + i*16 + lr) * 64 + slot * 8;
                const int offB = (wc*64 + i*16 + lr) * 64 + slot * 8;
                ah[i] = *(const bf16x8*)(smem + offA);
                bh[i] = *(const bf16x8*)(smem + (IN_SPLIT ? 16384 : 8192) + offB);
                if (IN_SPLIT) {
                    al[i] = *(const bf16x8*)(smem + 8192  + offA);
                    bl[i] = *(const bf16x8*)(smem + 24576 + offB);
                }
            }
#pragma unroll
            for (int i = 0; i < 4; ++i)
#pragma unroll
                for (int j = 0; j < 4; ++j) {
                    acc[i][j] = __builtin_amdgcn_mfma_f32_16x16x32_bf16(ah[i], bh[j], acc[i][j], 0, 0, 0);
                    if (IN_SPLIT) {
                        acc[i][j] = __builtin_amdgcn_mfma_f32_16x16x32_bf16(ah[i], bl[j], acc[i][j], 0, 0, 0);
                        acc[i][j] = __builtin_amdgcn_mfma_f32_16x16x32_bf16(al[i], bh[j], acc[i][j], 0, 0, 0);
                    }
                }
        }
        __syncthreads();
    }
    const int rb = lane >> 4;
    float bv[4];
    if (HAS_BIAS) {
#pragma unroll
        for (int j = 0; j < 4; ++j) bv[j] = bias[n0 + wc*64 + j*16 + lr];
    }
#pragma unroll
    for (int i = 0; i < 4; ++i)
#pragma unroll
        for (int e = 0; e < 4; ++e) {
            const int row = m0 + wr*64 + i*16 + rb*4 + e;
            if (row < M) {
#pragma unroll
                for (int j = 0; j < 4; ++j) {
                    const int colw = wc*64 + j*16 + lr;
                    float v = acc[i][j][e];
                    if (HAS_BIAS) v += bv[j];
                    if (!second) {
                        const int col = n0 + colw;
                        if (OM1 == 0) C1f[(size_t)row * N1 + col] = v;
                        else if (OM1 == 1) C1bf[(size_t)row * N1 + col] = f2bf(v);
                        else {
                            const int bidx = row / KStL, key = row - bidx * KStL;
                            C1bf[((size_t)bidx * N1 + col) * KStS + key] = f2bf(v);
                        }
                    } else {
                        const int col = nb + colw;
                        if (OM2 == 1) C2bf[(size_t)row * N2 + col] = f2bf(v);
                        else if (OM2 == 2) {
                            const int bidx = row / KStL, key = row - bidx * KStL;
                            C2bf[((size_t)bidx * N2 + col) * KStS + key] = f2bf(v);
                        }
                    }
                }
            }
        }
}

template<bool IN_SPLIT, int OM1, int OM2, bool HAS_BIAS>
__global__ __launch_bounds__(256, 2)
void gemm_mfma(const u16* __restrict__ Ah, const u16* __restrict__ Al,
               const u16* __restrict__ B1h, const u16* __restrict__ B1l,
               const u16* __restrict__ B2h,
               const float* __restrict__ bias, float* __restrict__ C1f,
               u16* __restrict__ C1bf, u16* __restrict__ C2bf,
               int M, int N1, int N2, int K, int KStL, int KStS) {
    __shared__ u16 smem[(IN_SPLIT ? 4 : 2) * 8192];
    gemm_body<IN_SPLIT,OM1,OM2,HAS_BIAS>(smem, blockIdx.x, blockIdx.y,
        Ah, Al, B1h, B1l, B2h, bias, C1f, C1bf, C2bf, M, N1, N2, K, KStL, KStS);
}

// All three K/V up-projection GEMMs in one launch.
__global__ __launch_bounds__(256, 2)
void kv_fused(const u16* __restrict__ lat, const u16* __restrict__ lp2,
              const u16* __restrict__ lp4,
              const u16* uk1T, const u16* uv1T, const u16* uk2T,
              const u16* uv2T, const u16* uk4T, const u16* uv4T,
              u16* k1, u16* v1t, u16* k2, u16* v2t, u16* k4, u16* v4t) {
    __shared__ u16 smem[2 * 8192];
    int bid = blockIdx.x;
    if (bid < 864) {
        gemm_body<false,1,2,false>(smem, bid % 12, bid / 12,
            lat, nullptr, uk1T, nullptr, uv1T, nullptr, nullptr, k1, v1t,
            9216, 768, 768, 256, 576, 576);
    } else if (bid < 1080) {
        bid -= 864;
        gemm_body<false,1,2,false>(smem, bid % 12, bid / 12,
            lp2, nullptr, uk2T, nullptr, uv2T, nullptr, nullptr, k2, v2t,
            2304, 768, 768, 256, 144, 144);
    } else {
        bid -= 1080;
        gemm_body<false,1,2,false>(smem, bid % 12, bid / 12,
            lp4, nullptr, uk4T, nullptr, uv4T, nullptr, nullptr, k4, v4t,
            576, 768, 768, 256, 36, 64);      // v4t padded to stride 64 (16B align)
    }
}

// ---------------------------------------------------------------------------
// Both mean pools from lat in one kernel. blocks [0,2304)=lp2, [2304,2880)=lp4
// ---------------------------------------------------------------------------
__global__ __launch_bounds__(256)
void pool_both(const u16* __restrict__ lat, u16* __restrict__ lp2,
               u16* __restrict__ lp4) {
    const int c = threadIdx.x;
    int id = blockIdx.x;
    if (id < 2304) {
        const int b = id / 144, g = id - b*144;
        const int gh = g / 12, gw = g - gh*12;
        const size_t i0 = (((size_t)(b*24 + gh*2))*24 + gw*2)*256 + c;
        const float s = (bf2f(lat[i0]) + bf2f(lat[i0+256]) +
                         bf2f(lat[i0+24*256]) + bf2f(lat[i0+24*256+256])) * 0.25f;
        lp2[(size_t)id*256 + c] = f2bf(s);
    } else {
        id -= 2304;
        const int b = id / 36, g = id - b*36;
        const int gh = g / 6, gw = g - gh*6;
        const size_t base = (((size_t)(b*24 + gh*4))*24 + gw*4)*256 + c;
        float s = 0.f;
#pragma unroll
        for (int i = 0; i < 4; ++i)
#pragma unroll
            for (int j = 0; j < 4; ++j)
                s += bf2f(lat[base + (size_t)(i*24 + j)*256]);
        lp4[(size_t)id*256 + c] = f2bf(s * (1.f/16.f));
    }
}

// ---------------------------------------------------------------------------
// Attention tile staging: global_load_lds into LINEAR [64 rows][64 cols] tile,
// source chunk pre-swizzled (chunk ^= row&7); reads use the same XOR.
// Each wave issues K slots {w,w+4} and V slots {w,w+4}: 4 gld_lds/wave/tile.
// ---------------------------------------------------------------------------
__device__ __forceinline__ void issue_tile(
    const u16* __restrict__ Kbf, const u16* __restrict__ Vt,
    int b, int h, int KS, int VSTR, int kt0,
    u16* Kdst, u16* Vdst, int wid, int lane)
{
    const int sub  = lane >> 3;                 // 0..7
    const int srcc = (lane & 7) ^ sub;          // source chunk swizzle
#pragma unroll
    for (int s = wid; s < 8; s += 4) {
        const int row = s*8 + sub;
        int gk = kt0 + row; gk = gk < KS ? gk : KS - 1;
        gld_lds16(Kbf + ((size_t)b*KS + gk)*768 + h*64 + srcc*8, Kdst + s*512);
    }
#pragma unroll
    for (int s = wid; s < 8; s += 4) {
        const int row = s*8 + sub;              // head dim
        gld_lds16(Vt + ((size_t)(b*768 + h*64 + row))*VSTR + kt0 + srcc*8,
                  Vdst + s*512);
    }
}

// ---------------------------------------------------------------------------
// One 64-key tile: QK (swapped operands), fixed-max log2 softmax, PV.
// Score layout: q = lr, keys = kt0 + g*16 + kg*4 + e.
// ---------------------------------------------------------------------------
template<int KS, int GW, int S>
__device__ __forceinline__ void attn_tile(
    int kt0, const u16* __restrict__ Kb, const u16* __restrict__ Vb,
    const u16* __restrict__ TblL, u16* __restrict__ PlW,
    int qh, int qw, int base1, int lr, int kg,
    const bf16x8 qa[2], f32x4 pacc[4], float& ls)
{
    constexpr int TW = 2*GW - 1;
    constexpr float C1 = 0.18033688011112042f;   // 0.125 * log2(e)

    f32x4 sf[4];
#pragma unroll
    for (int g = 0; g < 4; ++g) sf[g] = (f32x4)(0.f);
    __builtin_amdgcn_s_setprio(1);
#pragma unroll
    for (int ks = 0; ks < 2; ++ks)
#pragma unroll
        for (int g = 0; g < 4; ++g) {
            const int rc = (ks*4 + kg) ^ (lr & 7);
            const bf16x8 kb = *(const bf16x8*)(Kb + (g*16 + lr)*64 + rc*8);
            sf[g] = __builtin_amdgcn_mfma_f32_16x16x32_bf16(kb, qa[ks], sf[g], 0, 0, 0);
        }
    __builtin_amdgcn_s_setprio(0);

#pragma unroll
    for (int g = 0; g < 4; ++g) {
        const int key0 = kt0 + g*16 + kg*4;
        const bool v4 = ((KS % 64) == 0) || (key0 < KS);
        float pv[4];
        if (v4) {
            const int khi  = key0 / GW;
            const int kwi0 = key0 - khi*GW;
            if (S == 1) {
                const int idx0 = base1 - khi*TW - kwi0;
#pragma unroll
                for (int e = 0; e < 4; ++e)
                    pv[e] = exp2f_(fmaf(sf[g][e], C1, bf2f(TblL[idx0 - e])));
            } else if (S == 2) {
                const int dh = qh - 2*khi;
                const int rh = dh - (dh >= 1) + 23;
#pragma unroll
                for (int e = 0; e < 4; ++e) {
                    const int dw = qw - 2*(kwi0 + e);
                    const int rw = dw - (dw >= 1) + (GW - 1);
                    pv[e] = exp2f_(fmaf(sf[g][e], C1, bf2f(TblL[rh*TW + rw])));
                }
            } else {
#pragma unroll
                for (int e = 0; e < 4; ++e) {
                    int kk = kwi0 + e;
                    const int wrap = (kk >= GW);
                    kk -= wrap ? GW : 0;
                    const int kh2 = khi + wrap;
                    const int dh = qh - 4*kh2;
                    const int dw = qw - 4*kk;
                    const int rh = dh - 1 - (dh >= 2) + 23;
                    const int rw = dw - 1 - (dw >= 2) + (GW - 1);
                    pv[e] = exp2f_(fmaf(sf[g][e], C1, bf2f(TblL[rh*TW + rw])));
                }
            }
        } else {
            pv[0] = pv[1] = pv[2] = pv[3] = 0.f;
        }
        ls += (pv[0] + pv[1]) + (pv[2] + pv[3]);
        const unsigned int plo = (unsigned int)f2bf(pv[0]) | ((unsigned int)f2bf(pv[1]) << 16);
        const unsigned int phi = (unsigned int)f2bf(pv[2]) | ((unsigned int)f2bf(pv[3]) << 16);
        *(uint2*)&PlW[lr*72 + g*16 + kg*4] = make_uint2(plo, phi);
    }

    // out^T += V^T . P^T  (Pl same-wave write->read: DS in-order)
    __builtin_amdgcn_s_setprio(1);
#pragma unroll
    for (int ks = 0; ks < 2; ++ks) {
        const bf16x8 pb = *(const bf16x8*)(PlW + lr*72 + ks*32 + kg*8);
#pragma unroll
        for (int j = 0; j < 4; ++j) {
            const int rc = (ks*4 + kg) ^ (lr & 7);
            const bf16x8 vb = *(const bf16x8*)(Vb + (j*16 + lr)*64 + rc*8);
            pacc[j] = __builtin_amdgcn_mfma_f32_16x16x32_bf16(vb, pb, pacc[j], 0, 0, 0);
        }
    }
    __builtin_amdgcn_s_setprio(0);
}

__device__ __forceinline__ void fold3(f32x4 pacc[4], float& ls, f32x4 octx[4]) {
    float l = ls;
    l += __shfl_xor(l, 16);
    l += __shfl_xor(l, 32);
    const float inv = 1.0f / (3.0f * l);
#pragma unroll
    for (int j = 0; j < 4; ++j) {
#pragma unroll
        for (int e = 0; e < 4; ++e)
            octx[j][e] = fmaf(pacc[j][e], inv, octx[j][e]);
        pacc[j] = (f32x4)(0.f);
    }
    ls = 0.f;
}

// ---------------------------------------------------------------------------
// Fused 3-scale attention, software-pipelined: double-buffered K/V LDS tiles,
// raw s_barrier + counted vmcnt (one barrier per tile), prefetch across scale
// boundaries. Bias tables cached in LDS as bf16*log2e (RNE) -> total LDS
// 49.6 KB -> 3 blocks/CU. bid = qtile*192 + (b*12+h) keeps (b,h) on one XCD.
// ---------------------------------------------------------------------------
__global__ __launch_bounds__(256)
void attn_fused(const u16* __restrict__ Qbf,
                const u16* __restrict__ K1, const u16* __restrict__ V1t,
                const u16* __restrict__ K2, const u16* __restrict__ V2t,
                const u16* __restrict__ K4, const u16* __restrict__ V4t,
                const float* __restrict__ T1, const float* __restrict__ T2,
                const float* __restrict__ T4,
                u16* __restrict__ Ch, u16* __restrict__ Cl) {
    __shared__ u16 KlA[4096], KlB[4096], VlA[4096], VlB[4096];
    __shared__ u16 Pl[4][16*72];
    __shared__ u16 Tb[3807];            // [0)=s1 2209, [2209)=s2 1081, [3290)=s4 517
    const int tid  = threadIdx.x;
    const int wid  = tid >> 6;
    const int lane = tid & 63;
    const int lr   = lane & 15;
    const int kg   = lane >> 4;
    const int bid  = blockIdx.x;
    const int qt   = bid / 192;
    const int bh   = bid - qt*192;
    const int b    = bh / 12;
    const int h    = bh - b*12;
    const int qw0  = qt*64 + wid*16;
    const int q    = qw0 + lr;
    const int qh   = q / 24, qw = q - qh*24;
    const int base1 = (qh + 23)*47 + qw + 23;
    constexpr float LOG2E = 1.4426950408889634f;

    // prologue: issue tile0 loads, stage all 3 bias tables (bf16 RNE), drain
    issue_tile(K1, V1t, b, h, 576, 576, 0, KlA, VlA, wid, lane);
    for (int i = tid; i < 2209; i += 256) Tb[i]        = f2bf(T1[(size_t)h*2209 + i] * LOG2E);
    for (int i = tid; i < 1081; i += 256) Tb[2209 + i] = f2bf(T2[(size_t)h*1081 + i] * LOG2E);
    for (int i = tid; i < 517;  i += 256) Tb[3290 + i] = f2bf(T4[(size_t)h*517  + i] * LOG2E);
    asm volatile("s_waitcnt vmcnt(0) lgkmcnt(0)" ::: "memory");
    __builtin_amdgcn_s_barrier();
    __builtin_amdgcn_sched_barrier(0);

    bf16x8 qa[2];
    {
        const u16* qp = Qbf + ((size_t)(b*T_) + q)*768 + h*64 + kg*8;
        qa[0] = *(const bf16x8*)qp;
        qa[1] = *(const bf16x8*)(qp + 32);
    }
    f32x4 octx[4], pacc[4];
#pragma unroll
    for (int j = 0; j < 4; ++j) { octx[j] = (f32x4)(0.f); pacc[j] = (f32x4)(0.f); }
    float ls = 0.f;
    u16* PlW = &Pl[wid][0];

    // ---- scale 1: tiles 0..8 (tile t in buf (t&1?B:A)) ----
#pragma unroll 2
    for (int t = 0; t < 8; ++t) {
        issue_tile(K1, V1t, b, h, 576, 576, (t+1)*64,
                   (t&1) ? KlA : KlB, (t&1) ? VlA : VlB, wid, lane);
        attn_tile<576,24,1>(t*64, (t&1) ? KlB : KlA, (t&1) ? VlB : VlA,
                            Tb, PlW, qh, qw, base1, lr, kg, qa, pacc, ls);
        VMBAR();
    }
    issue_tile(K2, V2t, b, h, 144, 144, 0, KlB, VlB, wid, lane);      // t=8: cur A
    attn_tile<576,24,1>(512, KlA, VlA, Tb, PlW, qh, qw, base1, lr, kg, qa, pacc, ls);
    VMBAR();
    fold3(pacc, ls, octx);

    // ---- scale 2: tiles in B, A, B ----
    issue_tile(K2, V2t, b, h, 144, 144, 64, KlA, VlA, wid, lane);
    attn_tile<144,12,2>(0, KlB, VlB, Tb + 2209, PlW, qh, qw, 0, lr, kg, qa, pacc, ls);
    VMBAR();
    issue_tile(K2, V2t, b, h, 144, 144, 128, KlB, VlB, wid, lane);
    attn_tile<144,12,2>(64, KlA, VlA, Tb + 2209, PlW, qh, qw, 0, lr, kg, qa, pacc, ls);
    VMBAR();
    issue_tile(K4, V4t, b, h, 36, 64, 0, KlA, VlA, wid, lane);
    attn_tile<144,12,2>(128, KlB, VlB, Tb + 2209, PlW, qh, qw, 0, lr, kg, qa, pacc, ls);
    VMBAR();
    fold3(pacc, ls, octx);

    // ---- scale 4: one tile in A ----
    attn_tile<36,6,4>(0, KlA, VlA, Tb + 3290, PlW, qh, qw, 0, lr, kg, qa, pacc, ls);
    fold3(pacc, ls, octx);

    // epilogue: packed ushort4 split-bf16 stores
    const size_t rowoff = ((size_t)(b*T_) + q)*768 + h*64;
#pragma unroll
    for (int j = 0; j < 4; ++j) {
        u16 h0,h1,h2,h3, l0,l1,l2,l3;
        splitf(octx[j][0], h0, l0); splitf(octx[j][1], h1, l1);
        splitf(octx[j][2], h2, l2); splitf(octx[j][3], h3, l3);
        *(ushort4*)&Ch[rowoff + j*16 + kg*4] = make_ushort4(h0,h1,h2,h3);
        *(ushort4*)&Cl[rowoff + j*16 + kg*4] = make_ushort4(l0,l1,l2,l3);
    }
}

// ---------------------------------------------------------------------------
extern "C" void kernel_launch(void* const* d_in, const int* in_sizes, int n_in,
                              void* d_out, int out_size, void* d_ws, size_t ws_size,
                              hipStream_t stream) {
    const float* x    = (const float*)d_in[0];
    const float* wq   = (const float*)d_in[1];
    const float* wdkv = (const float*)d_in[2];
    const float* wuk1 = (const float*)d_in[3];
    const float* wuk2 = (const float*)d_in[4];
    const float* wuk4 = (const float*)d_in[5];
    const float* wuv1 = (const float*)d_in[6];
    const float* wuv2 = (const float*)d_in[7];
    const float* wuv4 = (const float*)d_in[8];
    const float* wout = (const float*)d_in[9];
    const float* bout = (const float*)d_in[10];
    const float* tbl1 = (const float*)d_in[11];
    const float* tbl2 = (const float*)d_in[12];
    const float* tbl4 = (const float*)d_in[13];

    u16* p = (u16*)d_ws;
    u16* x_bf   = p;            p += 7077888;
    u16* q_bf   = p;            p += 7077888;
    u16* lat_bf = p;            p += 2359296;
    u16* lp2_bf = p;            p += 589824;
    u16* lp4_bf = p;            p += 147456;
    u16* wqT    = p;            p += 589824;
    u16* wdkvT  = p;            p += 196608;
    u16* uk1T   = p;            p += 196608;
    u16* uv1T   = p;            p += 196608;
    u16* uk2T   = p;            p += 196608;
    u16* uv2T   = p;            p += 196608;
    u16* uk4T   = p;            p += 196608;
    u16* uv4T   = p;            p += 196608;
    u16* woutTh = p;            p += 589824;
    u16* woutTl = p;            p += 589824;
    u16* k1     = p;            p += 7077888;
    u16* v1t    = p;            p += 7077888;
    u16* k2     = p;            p += 1769472;
    u16* v2t    = p;            p += 1769472;
    u16* k4     = p;            p += 442368;
    u16* v4t    = p;            p += 786432;   // stride-64 padded
    u16* ctxh   = p;            p += 7077888;
    u16* ctxl   = p;            p += 7077888;
    float* outp = (float*)d_out;

    // conversions + weight prep (one kernel)
    prep_all<<<5952, 256, 0, stream>>>(x, x_bf, wq, wdkv, wuk1, wuv1, wuk2,
                                       wuv2, wuk4, wuv4, wout,
                                       wqT, wdkvT, uk1T, uv1T, uk2T, uv2T,
                                       uk4T, uv4T, woutTh, woutTl);

    // q + lat projections in one dual-N GEMM (N = 768 | 256)
    gemm_mfma<false,1,1,false><<<dim3(8,72), 256, 0, stream>>>(
        x_bf, nullptr, wqT, nullptr, wdkvT, nullptr, nullptr, q_bf, lat_bf,
        9216, 768, 256, 768, 0, 0);
    pool_both<<<2880, 256, 0, stream>>>(lat_bf, lp2_bf, lp4_bf);

    // all K|V up-projections in one launch
    kv_fused<<<1140, 256, 0, stream>>>(lat_bf, lp2_bf, lp4_bf,
                                       uk1T, uv1T, uk2T, uv2T, uk4T, uv4T,
                                       k1, v1t, k2, v2t, k4, v4t);

    // fused, pipelined 3-scale attention
    attn_fused<<<9*192, 256, 0, stream>>>(q_bf, k1, v1t, k2, v2t, k4, v4t,
                                          tbl1, tbl2, tbl4, ctxh, ctxl);

    // output projection (split inputs for fp32-grade accuracy)
    gemm_mfma<true,0,-1,true><<<dim3(6,72), 256, 0, stream>>>(
        ctxh, ctxl, woutTh, woutTl, nullptr, bout, outp, nullptr, nullptr,
        9216, 768, 0, 768, 0, 0);
}